// Round 4
// baseline (202.078 us; speedup 1.0000x reference)
//
#include <hip/hip_runtime.h>

// Y: 16384 x 2048 fp32 row-major. loss = sum_c |1 - (1/n) * sum_r Y[r][c]^2|
#define NROWS 16384
#define D     2048
#define D4    (D / 4)                        // 512 float4 per row
#define K1BLOCKS 1024                        // one contiguous 128KB slab each
#define ROWS_PER_BLOCK (NROWS / K1BLOCKS)    // 16 rows per slab
// P: [K1BLOCKS][D] floats = 8 MB partials in d_ws
// ws2: [32] floats of per-block loss partials, after P

// K1: block b streams rows [b*16, b*16+16) -- one fully contiguous 128 KB
// slab (the float4-copy access pattern). Thread t accumulates columns
// [4t,4t+3] (acc0) and [1024+4t,1024+4t+3] (acc1): per row it loads float4
// index t and 256+t, so the block covers each full 8KB row contiguously.
__global__ void __launch_bounds__(256)
colsq_partial(const float4* __restrict__ Y4, float4* __restrict__ P4) {
    const int t = threadIdx.x;
    const float4* p = Y4 + (size_t)blockIdx.x * ROWS_PER_BLOCK * D4 + t;
    float4 a0 = make_float4(0.f, 0.f, 0.f, 0.f);
    float4 a1 = make_float4(0.f, 0.f, 0.f, 0.f);
#pragma unroll 8
    for (int r = 0; r < ROWS_PER_BLOCK; ++r) {
        float4 v0 = p[(size_t)r * D4];
        float4 v1 = p[(size_t)r * D4 + 256];
        a0.x += v0.x * v0.x;  a0.y += v0.y * v0.y;
        a0.z += v0.z * v0.z;  a0.w += v0.w * v0.w;
        a1.x += v1.x * v1.x;  a1.y += v1.y * v1.y;
        a1.z += v1.z * v1.z;  a1.w += v1.w * v1.w;
    }
    float4* q = P4 + (size_t)blockIdx.x * D4;
    q[t]       = a0;
    q[t + 256] = a1;
}

// K2: reduce P over the 1024 stripes per column, apply |1 - s/n|, reduce
// 64 columns per block. grid 32 x 256: block b owns cols [b*64, b*64+64);
// 4 threads per column, each sums 256 stripes. Lanes read 64 consecutive
// floats per stripe-row (coalesced, L2/L3-resident).
__global__ void __launch_bounds__(256)
col_finalize(const float* __restrict__ P, float* __restrict__ ws2) {
    const int col  = blockIdx.x * 64 + (threadIdx.x & 63);
    const int part = threadIdx.x >> 6;                  // 0..3
    float s = 0.f;
#pragma unroll 8
    for (int i = 0; i < K1BLOCKS / 4; ++i) {
        int yb = part * (K1BLOCKS / 4) + i;
        s += P[(size_t)yb * D + col];
    }
    __shared__ float lds[256];
    lds[threadIdx.x] = s;
    __syncthreads();
    if (threadIdx.x < 64) {
        float tot = lds[threadIdx.x] + lds[threadIdx.x + 64] +
                    lds[threadIdx.x + 128] + lds[threadIdx.x + 192];
        float v = fabsf(1.0f - tot * (1.0f / (float)NROWS));
#pragma unroll
        for (int off = 32; off; off >>= 1)
            v += __shfl_down(v, off, 64);
        if (threadIdx.x == 0) ws2[blockIdx.x] = v;
    }
}

// K3: one wave sums the 32 block partials and writes the scalar.
__global__ void __launch_bounds__(64)
final_sum(const float* __restrict__ ws2, float* __restrict__ out) {
    float v = (threadIdx.x < 32) ? ws2[threadIdx.x] : 0.f;
#pragma unroll
    for (int off = 32; off; off >>= 1)
        v += __shfl_down(v, off, 64);
    if (threadIdx.x == 0) out[0] = v;
}

extern "C" void kernel_launch(void* const* d_in, const int* in_sizes, int n_in,
                              void* d_out, int out_size, void* d_ws, size_t ws_size,
                              hipStream_t stream) {
    const float4* Y4 = (const float4*)d_in[0];
    float* out = (float*)d_out;
    float* P   = (float*)d_ws;                               // 8 MB partials
    float* ws2 = (float*)((char*)d_ws + (size_t)K1BLOCKS * D * sizeof(float));

    colsq_partial<<<dim3(K1BLOCKS), 256, 0, stream>>>(Y4, (float4*)P);
    col_finalize<<<dim3(32), 256, 0, stream>>>(P, ws2);
    final_sum<<<dim3(1), 64, 0, stream>>>(ws2, out);
}